// Round 7
// baseline (180.565 us; speedup 1.0000x reference)
//
#include <hip/hip_runtime.h>
#include <math.h>

#define B 256
#define N 1152
#define C_ 10
#define OUT 16
#define IN 8
#define KO 160          // C_*OUT

// ---- s-partial geometry: 64-thread (1-wave) blocks, BT=4 rows/thread, all 10 k per block
#define MB 16           // batch rows per block
#define NC 9            // n per chunk
#define NCH 128         // N/NC
#define XSTR 84         // padded row stride (floats): 72+12, 16B-aligned, rows 2-way bank split

// partial[ch][b][k*16+o] = sum_{n in chunk} c[n,k]*(W[n,k,o,:].x[b,n,:])
// grid 2048 = 8 XCD * 16 ch * 16 bt, ALL co-resident (16 x 1-wave blocks/CU, LDS 5.8KB,
// VGPR target <=128). bt fastest within XCD: 16 consecutive blocks share one 46KB W chunk.
// BT=4: 34 FMA per W float4 load (was 17 at BT=2).
__global__ __launch_bounds__(64, 4) void k_s_partial(
    const float* __restrict__ x, const float* __restrict__ W,
    const float* __restrict__ c, float* __restrict__ partial)
{
    __shared__ float xs[MB][XSTR];      // 5.4 KB
    __shared__ float cs[NC][C_];        // 360 B

    const int tid = threadIdx.x;        // 0..63
    const int id  = blockIdx.x;
    const int g   = id & 7;             // XCD
    const int q   = id >> 3;            // 0..255
    const int bt  = q & 15;             // b-tile fastest on XCD -> W reuse
    const int chl = q >> 4;             // 0..15
    const int ch  = g * 16 + chl;       // 0..127
    const int b0  = bt * MB;
    const int n0  = ch * NC;

    // stage x tile: 16 rows x 18 float4 (72 contiguous floats each)
    for (int idx = tid; idx < MB * 18; idx += 64) {
        int bl = idx / 18, r = idx - bl * 18;
        float4 val = *(const float4*)(x + (size_t)(b0 + bl) * (N * IN) + (size_t)n0 * IN + r * 4);
        *(float4*)(&xs[bl][r * 4]) = val;
    }
    if (c) {
        for (int idx = tid; idx < NC * C_; idx += 64) {
            int nl = idx / C_, k = idx - nl * C_;
            cs[nl][k] = c[(size_t)(n0 + nl) * C_ + k];
        }
    }
    __syncthreads();

    const int o   = tid & 15;
    const int grp = (tid >> 4) * 4;     // rows grp..grp+3

    float acc[4][C_];
#pragma unroll
    for (int r = 0; r < 4; ++r)
#pragma unroll
        for (int k = 0; k < C_; ++k) acc[r][k] = 0.f;

    const float* Wb = W + (size_t)n0 * (KO * IN) + o * IN;

    for (int nl = 0; nl < NC; ++nl) {
        float4 xr[4][2];
#pragma unroll
        for (int r = 0; r < 4; ++r) {
            xr[r][0] = *(const float4*)(&xs[grp + r][nl * IN]);
            xr[r][1] = *(const float4*)(&xs[grp + r][nl * IN + 4]);
        }
        float cw[C_];
#pragma unroll
        for (int k = 0; k < C_; ++k) cw[k] = c ? cs[nl][k] : 0.1f;

        const float* Wn = Wb + (size_t)nl * (KO * IN);
#pragma unroll
        for (int k = 0; k < C_; ++k) {
            float4 w0 = *(const float4*)(Wn + k * (OUT * IN));
            float4 w1 = *(const float4*)(Wn + k * (OUT * IN) + 4);
#pragma unroll
            for (int r = 0; r < 4; ++r) {
                float d = w0.x * xr[r][0].x + w0.y * xr[r][0].y
                        + w0.z * xr[r][0].z + w0.w * xr[r][0].w
                        + w1.x * xr[r][1].x + w1.y * xr[r][1].y
                        + w1.z * xr[r][1].z + w1.w * xr[r][1].w;
                acc[r][k] += cw[k] * d;
            }
        }
    }

#pragma unroll
    for (int r = 0; r < 4; ++r) {
        float* pp = partial + (size_t)ch * (B * KO) + (size_t)(b0 + grp + r) * KO + o;
#pragma unroll
        for (int k = 0; k < C_; ++k) pp[k * OUT] = acc[r][k];
    }
}

// ---------------- reduce partials over 128 chunks + squash; wave-coalesced
// grid 640 x 256: block handles 64 elements; wave q sums chunks q*32..q*32+31
__global__ __launch_bounds__(256) void k_reduce_squash(
    const float* __restrict__ partial, float* __restrict__ v, float* __restrict__ out)
{
    __shared__ float red[256];
    const int tid = threadIdx.x;
    const int e   = blockIdx.x * 64 + (tid & 63);   // element 0..40959
    const int q   = tid >> 6;                       // wave 0..3
    float s = 0.f;
#pragma unroll
    for (int i = 0; i < NCH / 4; ++i)
        s += partial[(size_t)(q * (NCH / 4) + i) * (B * KO) + e];
    red[tid] = s;
    __syncthreads();
    if (q == 0) {
        s = red[tid] + red[tid + 64] + red[tid + 128] + red[tid + 192];
        float vv = s * fabsf(s) / (1.f + s * s);
        v[e] = vv;
        if (out) out[e] = vv;
    }
}

// ---------------- a-pass + fused softmax:
// bij[n][k] (+)= (1/B) sum_{b,o} (W[n,k,o,:].x[b,n,:]) * v[b,k,o];  c[n][:] = softmax(bij[n][:])
__global__ __launch_bounds__(256) void k_a_sm(
    const float* __restrict__ x, const float* __restrict__ W,
    const float* __restrict__ v, float* __restrict__ bij,
    float* __restrict__ c_out, int accumulate)
{
    const int n = blockIdx.x;
    const int tid = threadIdx.x;

    __shared__ float Wl[KO][IN + 1];      // padded
    __shared__ float xsl[B][IN];          // 8 KB
    __shared__ float red[4][16][C_];      // wave x o x k = 2.56 KB
    __shared__ float bnew[C_];

    for (int idx = tid; idx < KO * IN; idx += 256)
        Wl[idx >> 3][idx & 7] = W[(size_t)n * (KO * IN) + idx];
    for (int idx = tid; idx < B * IN / 4; idx += 256) {   // 512 float4
        int bb = idx >> 1, r = idx & 1;
        *(float4*)(&xsl[bb][r * 4]) = *(const float4*)(x + (size_t)bb * (N * IN) + (size_t)n * IN + r * 4);
    }
    __syncthreads();

    const int o = tid & 15;
    const int blane = tid >> 4;

    float part[C_];
#pragma unroll
    for (int k = 0; k < C_; ++k) part[k] = 0.f;

    for (int t = 0; t < B / 16; ++t) {
        int bb = blane + t * 16;
        float xv[IN];
#pragma unroll
        for (int i = 0; i < IN; ++i) xv[i] = xsl[bb][i];
        const float* vb = v + (size_t)bb * KO + o;
#pragma unroll
        for (int k = 0; k < C_; ++k) {
            const float* wp = &Wl[k * OUT + o][0];
            float d = 0.f;
#pragma unroll
            for (int i = 0; i < IN; ++i) d += wp[i] * xv[i];
            part[k] += d * vb[k * OUT];
        }
    }

    // wave-level reduce over the 4 blane groups in each wave (lanes: o=l&15, grp=l>>4)
    const int wv = tid >> 6;
#pragma unroll
    for (int k = 0; k < C_; ++k) {
        float p = part[k];
        p += __shfl_xor(p, 16);
        p += __shfl_xor(p, 32);
        part[k] = p;
    }
    if ((tid & 63) < 16) {
#pragma unroll
        for (int k = 0; k < C_; ++k) red[wv][o][k] = part[k];
    }
    __syncthreads();

    if (tid < C_) {   // thread per k: sum 4 waves x 16 o
        float a = 0.f;
#pragma unroll
        for (int w = 0; w < 4; ++w)
#pragma unroll
            for (int oo = 0; oo < 16; ++oo) a += red[w][oo][tid];
        a *= (1.0f / B);
        float bo = accumulate ? bij[(size_t)n * C_ + tid] : 0.f;
        float bn = bo + a;
        bij[(size_t)n * C_ + tid] = bn;
        bnew[tid] = bn;
    }
    __syncthreads();
    if (tid < C_) {   // redundant per-thread softmax over 10 values
        float m = -1e30f;
#pragma unroll
        for (int k = 0; k < C_; ++k) m = fmaxf(m, bnew[k]);
        float ssum = 0.f;
#pragma unroll
        for (int k = 0; k < C_; ++k) ssum += __expf(bnew[k] - m);
        c_out[(size_t)n * C_ + tid] = __expf(bnew[tid] - m) / ssum;
    }
}

extern "C" void kernel_launch(void* const* d_in, const int* in_sizes, int n_in,
                              void* d_out, int out_size, void* d_ws, size_t ws_size,
                              hipStream_t stream)
{
    const float* x = (const float*)d_in[0];   // [B, N, IN]
    const float* W = (const float*)d_in[1];   // [1, N, C, OUT, IN]
    float* out = (float*)d_out;               // [B, C, OUT, 1] = 40960 floats
    float* ws  = (float*)d_ws;

    float* part = ws;                         // 128 * 40960 = 5242880 floats (21 MB)
    float* bij  = ws + 5242880;               // 11520
    float* c    = bij + 11520;                // 11520
    float* v    = c + 11520;                  // 40960

    const int GS = 2048;

    // iteration 0: c = 1/C exactly (softmax of zeros); k_a_sm writes bij and c for iter 1
    k_s_partial<<<GS, 64, 0, stream>>>(x, W, nullptr, part);
    k_reduce_squash<<<640, 256, 0, stream>>>(part, v, nullptr);
    k_a_sm<<<N, 256, 0, stream>>>(x, W, v, bij, c, 0);

    // iteration 1
    k_s_partial<<<GS, 64, 0, stream>>>(x, W, c, part);
    k_reduce_squash<<<640, 256, 0, stream>>>(part, v, nullptr);
    k_a_sm<<<N, 256, 0, stream>>>(x, W, v, bij, c, 1);

    // iteration 2 (final: write d_out)
    k_s_partial<<<GS, 64, 0, stream>>>(x, W, c, part);
    k_reduce_squash<<<640, 256, 0, stream>>>(part, v, out);
}